// Round 3
// baseline (2031.494 us; speedup 1.0000x reference)
//
#include <hip/hip_runtime.h>
#include <hip/hip_bf16.h>
#include <math.h>

#define D 2048
#define H 256
#define E 16
#define TM 64          // tokens per block
#define BK 32          // k-chunk (split: kz half = 16)
#define LDW 36         // LDS row stride (floats); 144 B rows -> b128-aligned
#define THREADS 512
#define NCH (D / BK)   // 64 chunks
#define XS_OFF 0
#define WS_OFF (TM * LDW)        // 2304
#define SMEM_FLOATS 16384        // 64 KB (staging uses 11520; red4 uses all)
#define WS_STRIDE 20

__global__ __launch_bounds__(THREADS)
void router_main(const float* __restrict__ x, const float* __restrict__ Wp,
                 const float* __restrict__ Wg, const float* __restrict__ lnw_g,
                 const float* __restrict__ lnb_g, const float* __restrict__ temp_g,
                 float* __restrict__ out_rw, float* __restrict__ out_disp,
                 float* __restrict__ ws_part)
{
    __shared__ __align__(16) float smem[SMEM_FLOATS];
    const int t   = threadIdx.x;
    const int tx  = t & 15;          // h-lane / expert lane
    const int ty  = (t >> 4) & 15;   // token group: tokens 4*ty..4*ty+3
    const int kz  = t >> 8;          // split-k half (0/1)
    const int r8  = t >> 3;          // 0..63 staging row
    const int c8  = (t & 7) << 2;    // staging col (floats)
    const int tok0 = blockIdx.x * TM;

    float acc[4][16];
    #pragma unroll
    for (int i = 0; i < 4; ++i)
        #pragma unroll
        for (int j = 0; j < 16; ++j) acc[i][j] = 0.f;

    // register double-buffer staging: Wp tile 256x32 (4 f4/thr), x tile 64x32 (1 f4/thr)
    float4 wst[4], xst;
    auto ISSUE = [&](int k0) {
        #pragma unroll
        for (int p = 0; p < 4; ++p)
            wst[p] = *(const float4*)&Wp[(size_t)(p * 64 + r8) * D + k0 + c8];
        xst = *(const float4*)&x[(size_t)(tok0 + r8) * D + k0 + c8];
    };
    ISSUE(0);

    const float* xsp = &smem[XS_OFF + (4 * ty) * LDW + kz * 16];
    const float* wsp = &smem[WS_OFF + tx * LDW + kz * 16];

    for (int c = 0; c < NCH; ++c) {
        __syncthreads();                       // prior chunk's LDS reads done
        #pragma unroll
        for (int p = 0; p < 4; ++p)
            *(float4*)&smem[WS_OFF + (p * 64 + r8) * LDW + c8] = wst[p];
        *(float4*)&smem[XS_OFF + r8 * LDW + c8] = xst;
        __syncthreads();
        if (c + 1 < NCH) ISSUE((c + 1) * BK);  // prefetch under compute

        #pragma unroll
        for (int kk = 0; kk < 16; kk += 4) {   // this kz-half's 16 k-values
            float4 xa[4];
            #pragma unroll
            for (int i = 0; i < 4; ++i)
                xa[i] = *(const float4*)&xsp[i * LDW + kk];
            #pragma unroll
            for (int j = 0; j < 16; ++j) {
                const float4 w = *(const float4*)&wsp[j * 16 * LDW + kk];
                #pragma unroll
                for (int i = 0; i < 4; ++i) {
                    acc[i][j] = fmaf(xa[i].x, w.x, acc[i][j]);
                    acc[i][j] = fmaf(xa[i].y, w.y, acc[i][j]);
                    acc[i][j] = fmaf(xa[i].z, w.z, acc[i][j]);
                    acc[i][j] = fmaf(xa[i].w, w.w, acc[i][j]);
                }
            }
        }
    }

    // ---- cross-kz reduction: each side finishes 2 of its 4 tokens ----
    // kz0 finishes tokens {0,1}: writes partials of {2,3} at slots 8..15
    // kz1 finishes tokens {2,3}: writes partials of {0,1} at slots 0..7
    __syncthreads();
    float4* red4 = (float4*)smem;              // [16][256] float4 = 64 KB
    const int tid = t & 255;
    {
        const int jbase = kz ? 0 : 8;
        const int ibase = kz ? 0 : 2;
        #pragma unroll
        for (int m = 0; m < 8; ++m) {
            const int i = ibase + (m >> 2);
            const int q = (m & 3) * 4;
            red4[(jbase + m) * 256 + tid] =
                make_float4(acc[i][q], acc[i][q + 1], acc[i][q + 2], acc[i][q + 3]);
        }
    }
    __syncthreads();
    {
        const int jbase = kz ? 8 : 0;
        const int ibase = kz ? 2 : 0;
        #pragma unroll
        for (int m = 0; m < 8; ++m) {
            const int i = ibase + (m >> 2);
            const int q = (m & 3) * 4;
            const float4 r = red4[(jbase + m) * 256 + tid];
            acc[i][q] += r.x; acc[i][q + 1] += r.y; acc[i][q + 2] += r.z; acc[i][q + 3] += r.w;
        }
    }
    __syncthreads();

    // ---- post phase: Wg into LDS, then per-token LN/logits/softmax/top2 ----
    float* wg_s = smem;                         // [E][H] = 4096 floats
    float* lb_s = smem + 4096;                  // [16]
    float* z_s  = smem + 4112;                  // [1]
    #pragma unroll
    for (int p = 0; p < 2; ++p) {
        const int fi = (p * 512 + t) * 4;       // 1024 float4 total
        *(float4*)&wg_s[fi] = *(const float4*)&Wg[fi];
    }
    if (t < 16) lb_s[t] = 0.f;
    if (t == 16) z_s[0] = 0.f;
    __syncthreads();

    float lnw[16], lnb[16];
    #pragma unroll
    for (int j = 0; j < 16; ++j) {
        lnw[j] = lnw_g[tx + 16 * j];
        lnb[j] = lnb_g[tx + 16 * j];
    }
    const float temp = fabsf(temp_g[0]) + 1e-6f;

    float mylb = 0.f;
    float myz  = 0.f;

    #pragma unroll
    for (int i01 = 0; i01 < 2; ++i01) {
        const int a   = 2 * kz + i01;           // which acc row (full sum)
        const int tok = tok0 + 4 * ty + a;
        // mean over H
        float s = 0.f;
        #pragma unroll
        for (int j = 0; j < 16; ++j) s += acc[a][j];
        s += __shfl_xor(s, 1); s += __shfl_xor(s, 2);
        s += __shfl_xor(s, 4); s += __shfl_xor(s, 8);
        const float mu = s * (1.f / 256.f);
        // variance
        float v = 0.f;
        #pragma unroll
        for (int j = 0; j < 16; ++j) { const float d = acc[a][j] - mu; v = fmaf(d, d, v); }
        v += __shfl_xor(v, 1); v += __shfl_xor(v, 2);
        v += __shfl_xor(v, 4); v += __shfl_xor(v, 8);
        const float rstd = 1.0f / sqrtf(v * (1.f / 256.f) + 1e-5f);
        // normalized (strided h = tx + 16j)
        float n[16];
        #pragma unroll
        for (int j = 0; j < 16; ++j)
            n[j] = fmaf((acc[a][j] - mu) * rstd, lnw[j], lnb[j]);
        // logits partials over this lane's 16 h-columns
        float p[16];
        #pragma unroll
        for (int e = 0; e < 16; ++e) p[e] = 0.f;
        #pragma unroll
        for (int j = 0; j < 16; ++j) {
            const float nv = n[j];
            const int  h   = tx + 16 * j;
            #pragma unroll
            for (int e = 0; e < 16; ++e)
                p[e] = fmaf(nv, wg_s[e * H + h], p[e]);
        }
        // butterfly across the 16-lane group
        #pragma unroll
        for (int m = 1; m < 16; m <<= 1)
            #pragma unroll
            for (int e = 0; e < 16; ++e) p[e] += __shfl_xor(p[e], m);
        #pragma unroll
        for (int e = 0; e < 16; ++e) p[e] = p[e] / temp;
        // z-loss partial (one lane per token)
        if (tx == 0) {
            float z = 0.f;
            #pragma unroll
            for (int e = 0; e < 16; ++e) z = fmaf(p[e], p[e], z);
            myz += z;
        }
        // softmax (stable)
        float mx = p[0];
        #pragma unroll
        for (int e = 1; e < 16; ++e) mx = fmaxf(mx, p[e]);
        float w[16]; float sw = 0.f;
        #pragma unroll
        for (int e = 0; e < 16; ++e) { w[e] = expf(p[e] - mx); sw += w[e]; }
        #pragma unroll
        for (int e = 0; e < 16; ++e) w[e] = w[e] / sw;
        mylb += w[tx];
        // top-2 (ties -> lower index)
        float w1 = -1.f; int i1 = 0; float w2 = -1.f; int i2 = 0;
        #pragma unroll
        for (int e = 0; e < 16; ++e) {
            const float we = w[e];
            if (we > w1)      { w2 = w1; i2 = i1; w1 = we; i1 = e; }
            else if (we > w2) { w2 = we; i2 = e; }
        }
        const float rs = 1.f / (w1 + w2 + 1e-6f);
        const float v1 = w1 * rs, v2 = w2 * rs;
        out_rw  [(size_t)tok * E + tx] = w[tx];
        out_disp[(size_t)tok * E + tx] = (tx == i1) ? v1 : (tx == i2 ? v2 : 0.f);
    }

    atomicAdd(&lb_s[tx], mylb);
    if (tx == 0) atomicAdd(&z_s[0], myz);
    __syncthreads();
    if (t < 16)  ws_part[blockIdx.x * WS_STRIDE + t]  = lb_s[t];
    if (t == 16) ws_part[blockIdx.x * WS_STRIDE + 16] = z_s[0];
}

__global__ void router_final(const float* __restrict__ ws_part,
                             float* __restrict__ out_loss, int nblocks, int T)
{
    const int l = threadIdx.x;   // 64 threads
    float lb[16]; float z = 0.f;
    #pragma unroll
    for (int e = 0; e < 16; ++e) lb[e] = 0.f;
    for (int b = l; b < nblocks; b += 64) {
        #pragma unroll
        for (int e = 0; e < 16; ++e) lb[e] += ws_part[b * WS_STRIDE + e];
        z += ws_part[b * WS_STRIDE + 16];
    }
    #pragma unroll
    for (int m = 1; m < 64; m <<= 1) {
        #pragma unroll
        for (int e = 0; e < 16; ++e) lb[e] += __shfl_xor(lb[e], m);
        z += __shfl_xor(z, m);
    }
    if (l == 0) {
        const float zloss = z / (float)(T * 16);
        const float ideal = 1.f / 16.f;
        float lbl = 0.f;
        #pragma unroll
        for (int e = 0; e < 16; ++e) {
            const float a = lb[e] / (float)T;
            lbl += ideal * (logf(ideal) - logf(a));
        }
        lbl *= (1.f / 16.f);
        out_loss[0] = 0.005f * zloss + 0.005f * lbl;
    }
}

extern "C" void kernel_launch(void* const* d_in, const int* in_sizes, int n_in,
                              void* d_out, int out_size, void* d_ws, size_t ws_size,
                              hipStream_t stream)
{
    const float* x    = (const float*)d_in[0];
    const float* Wp   = (const float*)d_in[1];
    const float* Wg   = (const float*)d_in[2];
    const float* lnw  = (const float*)d_in[3];
    const float* lnb  = (const float*)d_in[4];
    const float* temp = (const float*)d_in[5];
    const int T = in_sizes[0] / D;           // 16384
    float* out      = (float*)d_out;
    float* out_rw   = out;
    float* out_disp = out + (size_t)T * E;
    float* out_loss = out + (size_t)2 * T * E;
    float* ws_part  = (float*)d_ws;
    const int nblocks = T / TM;              // 256

    hipLaunchKernelGGL(router_main, dim3(nblocks), dim3(THREADS), 0, stream,
                       x, Wp, Wg, lnw, lnb, temp, out_rw, out_disp, ws_part);
    hipLaunchKernelGGL(router_final, dim3(1), dim3(64), 0, stream,
                       ws_part, out_loss, nblocks, T);
}

// Round 4
// 373.378 us; speedup vs baseline: 5.4408x; 5.4408x over previous
//
#include <hip/hip_runtime.h>
#include <hip/hip_bf16.h>
#include <math.h>

#define D 2048
#define H 256
#define E 16
#define TM 64          // tokens per block
#define BK 32          // k-chunk (split: kz half = 16)
#define LDW 36         // LDS row stride (floats); 144 B rows -> b128-aligned
#define THREADS 512
#define NCH (D / BK)   // 64 chunks
#define XS_OFF 0
#define WS_OFF (TM * LDW)        // 2304
#define SMEM_FLOATS 16384        // 64 KB (staging uses 11520; red4 uses all)
#define WS_STRIDE 20

template <int N> struct IC { static constexpr int value = N; };

__global__ __launch_bounds__(THREADS)
void router_main(const float* __restrict__ x, const float* __restrict__ Wp,
                 const float* __restrict__ Wg, const float* __restrict__ lnw_g,
                 const float* __restrict__ lnb_g, const float* __restrict__ temp_g,
                 float* __restrict__ out_rw, float* __restrict__ out_disp,
                 float* __restrict__ ws_part)
{
    __shared__ __align__(16) float smem[SMEM_FLOATS];
    const int t   = threadIdx.x;
    const int tx  = t & 15;          // h-lane / expert lane
    const int ty  = (t >> 4) & 15;   // token group: tokens 4*ty..4*ty+3
    const int kz  = t >> 8;          // split-k half (0/1), wave-uniform
    const int r8  = t >> 3;          // 0..63 staging row
    const int c8  = (t & 7) << 2;    // staging col (floats)
    const int tok0 = blockIdx.x * TM;

    float acc[4][16];
    #pragma unroll
    for (int i = 0; i < 4; ++i)
        #pragma unroll
        for (int j = 0; j < 16; ++j) acc[i][j] = 0.f;

    // register double-buffer staging: Wp tile 256x32 (4 f4/thr), x tile 64x32 (1 f4/thr)
    float4 wst[4], xst;
    auto ISSUE = [&](int k0) {
        #pragma unroll
        for (int p = 0; p < 4; ++p)
            wst[p] = *(const float4*)&Wp[(size_t)(p * 64 + r8) * D + k0 + c8];
        xst = *(const float4*)&x[(size_t)(tok0 + r8) * D + k0 + c8];
    };
    ISSUE(0);

    const float* xsp = &smem[XS_OFF + (4 * ty) * LDW + kz * 16];
    const float* wsp = &smem[WS_OFF + tx * LDW + kz * 16];

    for (int c = 0; c < NCH; ++c) {
        __syncthreads();                       // prior chunk's LDS reads done
        #pragma unroll
        for (int p = 0; p < 4; ++p)
            *(float4*)&smem[WS_OFF + (p * 64 + r8) * LDW + c8] = wst[p];
        *(float4*)&smem[XS_OFF + r8 * LDW + c8] = xst;
        __syncthreads();
        if (c + 1 < NCH) ISSUE((c + 1) * BK);  // prefetch under compute

        #pragma unroll
        for (int kk = 0; kk < 16; kk += 4) {   // this kz-half's 16 k-values
            float4 xa[4];
            #pragma unroll
            for (int i = 0; i < 4; ++i)
                xa[i] = *(const float4*)&xsp[i * LDW + kk];
            #pragma unroll
            for (int j = 0; j < 16; ++j) {
                const float4 w = *(const float4*)&wsp[j * 16 * LDW + kk];
                #pragma unroll
                for (int i = 0; i < 4; ++i) {
                    acc[i][j] = fmaf(xa[i].x, w.x, acc[i][j]);
                    acc[i][j] = fmaf(xa[i].y, w.y, acc[i][j]);
                    acc[i][j] = fmaf(xa[i].z, w.z, acc[i][j]);
                    acc[i][j] = fmaf(xa[i].w, w.w, acc[i][j]);
                }
            }
        }
    }

    // ---- cross-kz reduction (ALL indices compile-time; kz wave-uniform) ----
    // kz0 finishes tokens {0,1}: writes partials of {2,3} at slots 8..15
    // kz1 finishes tokens {2,3}: writes partials of {0,1} at slots 0..7
    __syncthreads();
    float4* red4 = (float4*)smem;              // [16][256] float4 = 64 KB
    const int tid = t & 255;

    auto store_half = [&](auto kzc) {
        constexpr int KZ    = decltype(kzc)::value;
        constexpr int jbase = KZ ? 0 : 8;
        constexpr int ibase = KZ ? 0 : 2;
        #pragma unroll
        for (int m = 0; m < 8; ++m) {
            const int i = ibase + (m >> 2);    // folds after unroll
            const int q = (m & 3) * 4;
            red4[(jbase + m) * 256 + tid] =
                make_float4(acc[i][q], acc[i][q + 1], acc[i][q + 2], acc[i][q + 3]);
        }
    };
    if (kz == 0) store_half(IC<0>{}); else store_half(IC<1>{});
    __syncthreads();

    auto add_half = [&](auto kzc) {
        constexpr int KZ    = decltype(kzc)::value;
        constexpr int jbase = KZ ? 8 : 0;
        constexpr int ibase = KZ ? 2 : 0;
        #pragma unroll
        for (int m = 0; m < 8; ++m) {
            const int i = ibase + (m >> 2);
            const int q = (m & 3) * 4;
            const float4 r = red4[(jbase + m) * 256 + tid];
            acc[i][q] += r.x; acc[i][q + 1] += r.y; acc[i][q + 2] += r.z; acc[i][q + 3] += r.w;
        }
    };
    if (kz == 0) add_half(IC<0>{}); else add_half(IC<1>{});
    __syncthreads();

    // ---- post phase: Wg into LDS, then per-token LN/logits/softmax/top2 ----
    float* wg_s = smem;                         // [E][H] = 4096 floats
    float* lb_s = smem + 4096;                  // [16]
    float* z_s  = smem + 4112;                  // [1]
    #pragma unroll
    for (int p = 0; p < 2; ++p) {
        const int fi = (p * 512 + t) * 4;       // 1024 float4 total
        *(float4*)&wg_s[fi] = *(const float4*)&Wg[fi];
    }
    if (t < 16) lb_s[t] = 0.f;
    if (t == 16) z_s[0] = 0.f;
    __syncthreads();

    float lnw[16], lnb[16];
    #pragma unroll
    for (int j = 0; j < 16; ++j) {
        lnw[j] = lnw_g[tx + 16 * j];
        lnb[j] = lnb_g[tx + 16 * j];
    }
    const float temp = fabsf(temp_g[0]) + 1e-6f;

    float mylb = 0.f;
    float myz  = 0.f;

    auto post_half = [&](auto kzc) {
        constexpr int KZ = decltype(kzc)::value;
        #pragma unroll
        for (int i01 = 0; i01 < 2; ++i01) {
            const int a   = 2 * KZ + i01;       // compile-time after unroll
            const int tok = tok0 + 4 * ty + a;
            // mean over H
            float s = 0.f;
            #pragma unroll
            for (int j = 0; j < 16; ++j) s += acc[a][j];
            s += __shfl_xor(s, 1); s += __shfl_xor(s, 2);
            s += __shfl_xor(s, 4); s += __shfl_xor(s, 8);
            const float mu = s * (1.f / 256.f);
            // variance
            float v = 0.f;
            #pragma unroll
            for (int j = 0; j < 16; ++j) { const float d = acc[a][j] - mu; v = fmaf(d, d, v); }
            v += __shfl_xor(v, 1); v += __shfl_xor(v, 2);
            v += __shfl_xor(v, 4); v += __shfl_xor(v, 8);
            const float rstd = 1.0f / sqrtf(v * (1.f / 256.f) + 1e-5f);
            // normalized (strided h = tx + 16j)
            float n[16];
            #pragma unroll
            for (int j = 0; j < 16; ++j)
                n[j] = fmaf((acc[a][j] - mu) * rstd, lnw[j], lnb[j]);
            // logits partials over this lane's 16 h-columns
            float p[16];
            #pragma unroll
            for (int e = 0; e < 16; ++e) p[e] = 0.f;
            #pragma unroll
            for (int j = 0; j < 16; ++j) {
                const float nv = n[j];
                const int  h   = tx + 16 * j;
                #pragma unroll
                for (int e = 0; e < 16; ++e)
                    p[e] = fmaf(nv, wg_s[e * H + h], p[e]);
            }
            // butterfly across the 16-lane group
            #pragma unroll
            for (int m = 1; m < 16; m <<= 1)
                #pragma unroll
                for (int e = 0; e < 16; ++e) p[e] += __shfl_xor(p[e], m);
            #pragma unroll
            for (int e = 0; e < 16; ++e) p[e] = p[e] / temp;
            // z-loss partial (one lane per token)
            if (tx == 0) {
                float z = 0.f;
                #pragma unroll
                for (int e = 0; e < 16; ++e) z = fmaf(p[e], p[e], z);
                myz += z;
            }
            // softmax (stable)
            float mx = p[0];
            #pragma unroll
            for (int e = 1; e < 16; ++e) mx = fmaxf(mx, p[e]);
            float w[16]; float sw = 0.f;
            #pragma unroll
            for (int e = 0; e < 16; ++e) { w[e] = expf(p[e] - mx); sw += w[e]; }
            #pragma unroll
            for (int e = 0; e < 16; ++e) w[e] = w[e] / sw;
            mylb += w[tx];
            // top-2 (ties -> lower index)
            float w1 = -1.f; int i1 = 0; float w2 = -1.f; int i2 = 0;
            #pragma unroll
            for (int e = 0; e < 16; ++e) {
                const float we = w[e];
                if (we > w1)      { w2 = w1; i2 = i1; w1 = we; i1 = e; }
                else if (we > w2) { w2 = we; i2 = e; }
            }
            const float rs = 1.f / (w1 + w2 + 1e-6f);
            const float v1 = w1 * rs, v2 = w2 * rs;
            out_rw  [(size_t)tok * E + tx] = w[tx];
            out_disp[(size_t)tok * E + tx] = (tx == i1) ? v1 : (tx == i2 ? v2 : 0.f);
        }
    };
    if (kz == 0) post_half(IC<0>{}); else post_half(IC<1>{});

    atomicAdd(&lb_s[tx], mylb);
    if (tx == 0) atomicAdd(&z_s[0], myz);
    __syncthreads();
    if (t < 16)  ws_part[blockIdx.x * WS_STRIDE + t]  = lb_s[t];
    if (t == 16) ws_part[blockIdx.x * WS_STRIDE + 16] = z_s[0];
}

__global__ void router_final(const float* __restrict__ ws_part,
                             float* __restrict__ out_loss, int nblocks, int T)
{
    const int l = threadIdx.x;   // 64 threads
    float lb[16]; float z = 0.f;
    #pragma unroll
    for (int e = 0; e < 16; ++e) lb[e] = 0.f;
    for (int b = l; b < nblocks; b += 64) {
        #pragma unroll
        for (int e = 0; e < 16; ++e) lb[e] += ws_part[b * WS_STRIDE + e];
        z += ws_part[b * WS_STRIDE + 16];
    }
    #pragma unroll
    for (int m = 1; m < 64; m <<= 1) {
        #pragma unroll
        for (int e = 0; e < 16; ++e) lb[e] += __shfl_xor(lb[e], m);
        z += __shfl_xor(z, m);
    }
    if (l == 0) {
        const float zloss = z / (float)(T * 16);
        const float ideal = 1.f / 16.f;
        float lbl = 0.f;
        #pragma unroll
        for (int e = 0; e < 16; ++e) {
            const float a = lb[e] / (float)T;
            lbl += ideal * (logf(ideal) - logf(a));
        }
        lbl *= (1.f / 16.f);
        out_loss[0] = 0.005f * zloss + 0.005f * lbl;
    }
}

extern "C" void kernel_launch(void* const* d_in, const int* in_sizes, int n_in,
                              void* d_out, int out_size, void* d_ws, size_t ws_size,
                              hipStream_t stream)
{
    const float* x    = (const float*)d_in[0];
    const float* Wp   = (const float*)d_in[1];
    const float* Wg   = (const float*)d_in[2];
    const float* lnw  = (const float*)d_in[3];
    const float* lnb  = (const float*)d_in[4];
    const float* temp = (const float*)d_in[5];
    const int T = in_sizes[0] / D;           // 16384
    float* out      = (float*)d_out;
    float* out_rw   = out;
    float* out_disp = out + (size_t)T * E;
    float* out_loss = out + (size_t)2 * T * E;
    float* ws_part  = (float*)d_ws;
    const int nblocks = T / TM;              // 256

    hipLaunchKernelGGL(router_main, dim3(nblocks), dim3(THREADS), 0, stream,
                       x, Wp, Wg, lnw, lnb, temp, out_rw, out_disp, ws_part);
    hipLaunchKernelGGL(router_final, dim3(1), dim3(64), 0, stream,
                       ws_part, out_loss, nblocks, T);
}